// Round 2
// baseline (724.226 us; speedup 1.0000x reference)
//
#include <hip/hip_runtime.h>
#include <hip/hip_bf16.h>

#define N 2048
#define D 128
#define H 40

typedef __attribute__((ext_vector_type(8))) short short8;
typedef __attribute__((ext_vector_type(4))) float float4v;
typedef __attribute__((ext_vector_type(16))) float float16v;

static __device__ __forceinline__ unsigned short f32_to_bf16(float f) {
  unsigned int u = __builtin_bit_cast(unsigned int, f);
  unsigned int rounding = 0x7FFFu + ((u >> 16) & 1u);
  return (unsigned short)((u + rounding) >> 16);
}

static __device__ __forceinline__ unsigned long long pack4(float x0, float x1,
                                                           float x2, float x3) {
  return (unsigned long long)f32_to_bf16(x0) |
         ((unsigned long long)f32_to_bf16(x1) << 16) |
         ((unsigned long long)f32_to_bf16(x2) << 32) |
         ((unsigned long long)f32_to_bf16(x3) << 48);
}

// X (fp32) -> Xb (bf16). 262144 elements, 128 blocks x 256 thr x 8 elem.
__global__ __launch_bounds__(256)
void xconv_kernel(const float* __restrict__ X, unsigned short* __restrict__ Xb) {
  int i = (blockIdx.x * 256 + threadIdx.x) * 8;
  float4v a = *(const float4v*)(X + i);
  float4v b = *(const float4v*)(X + i + 4);
  *(unsigned long long*)(Xb + i) = pack4(a.x, a.y, a.z, a.w);
  *(unsigned long long*)(Xb + i + 4) = pack4(b.x, b.y, b.z, b.w);
}

// Per (128-row tile, head): Qg[h][n][e] = X @ (W[h]/sqrt(D));
// XVT[h][e][n] = (X @ V[h])^T.  32x32x16 MFMA; W/V staged transposed in LDS.
__global__ __launch_bounds__(256)
void prep_kernel(const float* __restrict__ Wf, const float* __restrict__ Vf,
                 const unsigned short* __restrict__ Xb,
                 unsigned short* __restrict__ Qg, unsigned short* __restrict__ XVT) {
  const int h = blockIdx.y;
  const int n0 = blockIdx.x * 128;
  const int tid = threadIdx.x;
  const int wave = tid >> 6, lane = tid & 63;
  const int l = lane & 31, hh = lane >> 5;

  __shared__ __align__(16) unsigned short Ts[128 * 136];  // [e][d], reused as Ls[e][n]

  // A-fragments (X rows) straight from global bf16.
  short8 af[8];
#pragma unroll
  for (int ks = 0; ks < 8; ks++)
    af[ks] = *(const short8*)(Xb + (size_t)(n0 + wave * 32 + l) * D + ks * 16 + hh * 8);

  for (int mat = 0; mat < 2; mat++) {
    const float* M = (mat ? Vf : Wf) + (size_t)h * D * D;
    const float scale = mat ? 1.0f : 0.08838834764831845f;  // 1/sqrt(128)
    __syncthreads();
    for (int i = tid; i < 128 * 32; i += 256) {
      int d = i >> 5, c4 = (i & 31) * 4;
      float4v w = *(const float4v*)(M + d * D + c4);
      Ts[(c4 + 0) * 136 + d] = f32_to_bf16(w.x * scale);
      Ts[(c4 + 1) * 136 + d] = f32_to_bf16(w.y * scale);
      Ts[(c4 + 2) * 136 + d] = f32_to_bf16(w.z * scale);
      Ts[(c4 + 3) * 136 + d] = f32_to_bf16(w.w * scale);
    }
    __syncthreads();

    float16v acc[4];
#pragma unroll
    for (int et = 0; et < 4; et++) acc[et] = (float16v)(0.0f);
#pragma unroll
    for (int et = 0; et < 4; et++)
#pragma unroll
      for (int ks = 0; ks < 8; ks++) {
        short8 b = *(const short8*)(Ts + (et * 32 + l) * 136 + ks * 16 + hh * 8);
        acc[et] = __builtin_amdgcn_mfma_f32_32x32x16_bf16(af[ks], b, acc[et], 0, 0, 0);
      }

    if (mat == 0) {
      // C: row = n-local, col = e. Store row-major Q (coalesced over lanes).
#pragma unroll
      for (int et = 0; et < 4; et++)
#pragma unroll
        for (int r = 0; r < 16; r++) {
          int n = n0 + wave * 32 + (r & 3) + 8 * (r >> 2) + 4 * hh;
          int e = et * 32 + l;
          Qg[((size_t)h * N + n) * D + e] = f32_to_bf16(acc[et][r]);
        }
    } else {
      __syncthreads();  // everyone done reading Ts(V)
      // Transpose through LDS: Ls[e][n-local], packed b64 writes.
#pragma unroll
      for (int et = 0; et < 4; et++)
#pragma unroll
        for (int g = 0; g < 4; g++) {
          int nl = wave * 32 + 8 * g + 4 * hh;
          *(unsigned long long*)(Ts + (et * 32 + l) * 136 + nl) =
              pack4(acc[et][4 * g + 0], acc[et][4 * g + 1],
                    acc[et][4 * g + 2], acc[et][4 * g + 3]);
        }
      __syncthreads();
      for (int i = tid; i < 2048; i += 256) {
        int e = i >> 4, c = (i & 15) * 8;
        *(uint4*)(XVT + ((size_t)h * D + e) * N + n0 + c) =
            *(const uint4*)(Ts + e * 136 + c);
      }
    }
  }
}

// Attention: 1-D grid 640 blocks, head = id%40 (XCD-local heads), 4 waves,
// wave = 32 q rows. Zero barriers: K/V/Q frags from L2; LDS only for the
// wave-private P round-trip. No max-subtraction (|scores| < ~0.7).
__global__ __launch_bounds__(256)
void attn_kernel(const unsigned short* __restrict__ Xb,
                 const unsigned short* __restrict__ Qg,
                 const unsigned short* __restrict__ XVT,
                 float* __restrict__ out) {
  const int h = blockIdx.x % H;
  const int q0 = (blockIdx.x / H) * 128;
  const int tid = threadIdx.x;
  const int wave = tid >> 6, lane = tid & 63;
  const int l = lane & 31, hh = lane >> 5;
  const int q = q0 + wave * 32 + l;  // this lane's q column

  __shared__ __align__(16) unsigned short Ps[128 * 72];  // [q-local][key], pad 8
  unsigned short* Pr = Ps + (wave * 32 + l) * 72;

  short8 qf[8];
#pragma unroll
  for (int ks = 0; ks < 8; ks++)
    qf[ks] = *(const short8*)(Qg + ((size_t)h * N + q) * D + ks * 16 + hh * 8);

  const unsigned short* Xv = XVT + (size_t)h * D * N;

  float16v oacc[4];
#pragma unroll
  for (int et = 0; et < 4; et++) oacc[et] = (float16v)(0.0f);
  float lsum = 0.0f;

  for (int k0 = 0; k0 < N; k0 += 64) {
    // S^T = K @ Q^T for 64 keys x 32 q (two 32-key subtiles).
#pragma unroll
    for (int n = 0; n < 2; n++) {
      float16v s = (float16v)(0.0f);
#pragma unroll
      for (int ks = 0; ks < 8; ks++) {
        short8 kf = *(const short8*)(Xb + (size_t)(k0 + n * 32 + l) * D + ks * 16 + hh * 8);
        s = __builtin_amdgcn_mfma_f32_32x32x16_bf16(kf, qf[ks], s, 0, 0, 0);
      }
      // exp (no max-sub), accumulate row sum, pack 4 consecutive keys -> b64.
#pragma unroll
      for (int g = 0; g < 4; g++) {
        float p0 = __expf(s[4 * g + 0]);
        float p1 = __expf(s[4 * g + 1]);
        float p2 = __expf(s[4 * g + 2]);
        float p3 = __expf(s[4 * g + 3]);
        lsum += (p0 + p1) + (p2 + p3);
        *(unsigned long long*)(Pr + n * 32 + 8 * g + 4 * hh) = pack4(p0, p1, p2, p3);
      }
    }
    // O^T += XVT @ P^T  (wave-private P; compiler's lgkmcnt orders LDS ops).
#pragma unroll
    for (int kk = 0; kk < 4; kk++) {
      short8 pf = *(const short8*)(Pr + kk * 16 + hh * 8);
#pragma unroll
      for (int et = 0; et < 4; et++) {
        short8 vf = *(const short8*)(Xv + (size_t)(et * 32 + l) * N + k0 + kk * 16 + hh * 8);
        oacc[et] = __builtin_amdgcn_mfma_f32_32x32x16_bf16(vf, pf, oacc[et], 0, 0, 0);
      }
    }
  }

  float lt = lsum + __shfl_xor(lsum, 32);
  float inv = 1.0f / lt;
#pragma unroll
  for (int et = 0; et < 4; et++)
#pragma unroll
    for (int r = 0; r < 16; r++) {
      int e = et * 32 + (r & 3) + 8 * (r >> 2) + 4 * hh;
      atomicAdd(out + (size_t)q * D + e, oacc[et][r] * inv);
    }
}

extern "C" void kernel_launch(void* const* d_in, const int* in_sizes, int n_in,
                              void* d_out, int out_size, void* d_ws, size_t ws_size,
                              hipStream_t stream) {
  const float* X = (const float*)d_in[0];
  const float* W = (const float*)d_in[1];
  const float* V = (const float*)d_in[2];
  float* out = (float*)d_out;

  unsigned short* Xb = (unsigned short*)d_ws;   // N*D
  unsigned short* Qg = Xb + (size_t)N * D;      // H*N*D
  unsigned short* XVT = Qg + (size_t)H * N * D; // H*D*N

  hipMemsetAsync(d_out, 0, (size_t)N * D * sizeof(float), stream);

  xconv_kernel<<<dim3(N * D / (256 * 8)), 256, 0, stream>>>(X, Xb);
  prep_kernel<<<dim3(N / 128, H), 256, 0, stream>>>(W, V, Xb, Qg, XVT);
  attn_kernel<<<dim3((N / 128) * H), 256, 0, stream>>>(Xb, Qg, XVT, out);
}

// Round 3
// 511.905 us; speedup vs baseline: 1.4148x; 1.4148x over previous
//
#include <hip/hip_runtime.h>
#include <hip/hip_bf16.h>
#include <stdint.h>

#define N 2048
#define D 128
#define H 40

typedef __attribute__((ext_vector_type(8))) short short8;
typedef __attribute__((ext_vector_type(4))) float float4v;
typedef __attribute__((ext_vector_type(16))) float float16v;

static __device__ __forceinline__ unsigned short f32_to_bf16(float f) {
  unsigned int u = __builtin_bit_cast(unsigned int, f);
  unsigned int rounding = 0x7FFFu + ((u >> 16) & 1u);
  return (unsigned short)((u + rounding) >> 16);
}

static __device__ __forceinline__ unsigned int pk2(float lo, float hi) {
  return (unsigned int)f32_to_bf16(lo) | ((unsigned int)f32_to_bf16(hi) << 16);
}

static __device__ __forceinline__ unsigned long long pack4(float x0, float x1,
                                                           float x2, float x3) {
  return (unsigned long long)pk2(x0, x1) | ((unsigned long long)pk2(x2, x3) << 32);
}

// Async global->LDS DMA, 16B/lane. LDS dest = wave-uniform base + lane*16.
static __device__ __forceinline__ void load_lds16(const void* g, void* l) {
  __builtin_amdgcn_global_load_lds(
      (const __attribute__((address_space(1))) unsigned int*)g,
      (__attribute__((address_space(3))) unsigned int*)l, 16, 0, 0);
}

#define MFMA32(a, b, c) __builtin_amdgcn_mfma_f32_32x32x16_bf16((a), (b), (c), 0, 0, 0)

// Convert 32x32 C-layout regs (m=(r&3)+8*(r>>2)+4*hh, col=l) into two
// B-fragments (k=hh*8+j): f0 covers m=0..15, f1 covers m=16..31.
static __device__ __forceinline__ void regs_to_bfrags(const float16v c, int hh,
                                                      short8& f0, short8& f1) {
  unsigned int a0 = pk2(c[0], c[1]),   a1 = pk2(c[2], c[3]);
  unsigned int a2 = pk2(c[4], c[5]),   a3 = pk2(c[6], c[7]);
  unsigned int a4 = pk2(c[8], c[9]),   a5 = pk2(c[10], c[11]);
  unsigned int a6 = pk2(c[12], c[13]), a7 = pk2(c[14], c[15]);
  unsigned int x0 = __shfl_xor(hh ? a0 : a2, 32);
  unsigned int x1 = __shfl_xor(hh ? a1 : a3, 32);
  unsigned int x2 = __shfl_xor(hh ? a4 : a6, 32);
  unsigned int x3 = __shfl_xor(hh ? a5 : a7, 32);
  uint4 u0 = {hh ? x0 : a0, hh ? x1 : a1, hh ? a2 : x0, hh ? a3 : x1};
  uint4 u1 = {hh ? x2 : a4, hh ? x3 : a5, hh ? a6 : x2, hh ? a7 : x3};
  f0 = __builtin_bit_cast(short8, u0);
  f1 = __builtin_bit_cast(short8, u1);
}

// Same, but exp() first and accumulate the row-sum (softmax denominator).
static __device__ __forceinline__ void regs_to_pfrags(const float16v s, int hh,
                                                      float& lsum, short8& f0,
                                                      short8& f1) {
  float e[16];
  float acc = 0.0f;
#pragma unroll
  for (int i = 0; i < 16; i++) { e[i] = __expf(s[i]); acc += e[i]; }
  lsum += acc;
  unsigned int a0 = pk2(e[0], e[1]),   a1 = pk2(e[2], e[3]);
  unsigned int a2 = pk2(e[4], e[5]),   a3 = pk2(e[6], e[7]);
  unsigned int a4 = pk2(e[8], e[9]),   a5 = pk2(e[10], e[11]);
  unsigned int a6 = pk2(e[12], e[13]), a7 = pk2(e[14], e[15]);
  unsigned int x0 = __shfl_xor(hh ? a0 : a2, 32);
  unsigned int x1 = __shfl_xor(hh ? a1 : a3, 32);
  unsigned int x2 = __shfl_xor(hh ? a4 : a6, 32);
  unsigned int x3 = __shfl_xor(hh ? a5 : a7, 32);
  uint4 u0 = {hh ? x0 : a0, hh ? x1 : a1, hh ? a2 : x0, hh ? a3 : x1};
  uint4 u1 = {hh ? x2 : a4, hh ? x3 : a5, hh ? a6 : x2, hh ? a7 : x3};
  f0 = __builtin_bit_cast(short8, u0);
  f1 = __builtin_bit_cast(short8, u1);
}

// ---------------- X fp32 -> bf16 ----------------
__global__ __launch_bounds__(256)
void xconv_kernel(const float* __restrict__ X, unsigned short* __restrict__ Xb) {
  int i = (blockIdx.x * 256 + threadIdx.x) * 8;
  float4v a = *(const float4v*)(X + i);
  float4v b = *(const float4v*)(X + i + 4);
  *(unsigned long long*)(Xb + i) = pack4(a.x, a.y, a.z, a.w);
  *(unsigned long long*)(Xb + i + 4) = pack4(b.x, b.y, b.z, b.w);
}

// ------------- W/V fp32 -> bf16, transposed: Wt[h][e][d] -------------
__global__ __launch_bounds__(256)
void wvconv_kernel(const float* __restrict__ W, const float* __restrict__ V,
                   unsigned short* __restrict__ Wt, unsigned short* __restrict__ Vt) {
  const int b = blockIdx.x;
  const int mat = (b >= H) ? 1 : 0;
  const int h = mat ? b - H : b;
  const float* src = (mat ? V : W) + (size_t)h * D * D;
  unsigned short* dst = (mat ? Vt : Wt) + (size_t)h * D * D;
  const float scale = mat ? 1.0f : 0.08838834764831845f;  // 1/sqrt(128) folded into W
  const int tid = threadIdx.x;
  __shared__ __align__(16) unsigned short Lt[128 * 136];  // [e][d], pad 8
  for (int i = tid; i < 128 * 32; i += 256) {
    int d = i >> 5, e4 = (i & 31) * 4;
    float4v w = *(const float4v*)(src + d * D + e4);
    Lt[(e4 + 0) * 136 + d] = f32_to_bf16(w.x * scale);
    Lt[(e4 + 1) * 136 + d] = f32_to_bf16(w.y * scale);
    Lt[(e4 + 2) * 136 + d] = f32_to_bf16(w.z * scale);
    Lt[(e4 + 3) * 136 + d] = f32_to_bf16(w.w * scale);
  }
  __syncthreads();
  for (int i = tid; i < 128 * 16; i += 256) {
    int e = i >> 4, u = i & 15;
    *(uint4*)((char*)dst + (size_t)e * 256 + u * 16) =
        *(const uint4*)((const char*)Lt + (size_t)e * 272 + u * 16);
  }
}

// ------------- XVT[h][e][n] = (X @ V[h])^T, bf16, MFMA -------------
__global__ __launch_bounds__(256, 2)
void prep_kernel(const unsigned short* __restrict__ Xb,
                 const unsigned short* __restrict__ Vt,
                 unsigned short* __restrict__ XVT) {
  __shared__ __align__(16) char smem[65536];  // [0,32K)=X tile / out Ls, [32K,64K)=Vt
  const int bx = blockIdx.x;
  const int h = bx >> 4;
  const int n0 = (bx & 15) << 7;
  const int tid = threadIdx.x;
  const int wave = tid >> 6, lane = tid & 63;
  const int l = lane & 31, hh = lane >> 5, xk = l & 7;
  const int lh = lane >> 4, lu = lane & 15;
  const int nw = wave & 1, ew = wave >> 1;

  const char* XbB = (const char*)Xb;
  const char* VtB = (const char*)(Vt + (size_t)h * D * D);

  // Stage X rows n0..n0+127 (swizzled) and Vt[h] (swizzled) via DMA.
#pragma unroll
  for (int i = 0; i < 8; i++) {
    int r = wave * 32 + i * 4 + lh;
    int usrc = lu ^ (r & 7);
    load_lds16(XbB + (size_t)(n0 + r) * 256 + usrc * 16, smem + (wave * 8 + i) * 1024);
    load_lds16(VtB + (size_t)r * 256 + usrc * 16, smem + 32768 + (wave * 8 + i) * 1024);
  }
  __syncthreads();

  float16v acc[2][2];  // [nt][ec]
#pragma unroll
  for (int nt = 0; nt < 2; nt++)
#pragma unroll
    for (int ec = 0; ec < 2; ec++) acc[nt][ec] = (float16v)0.0f;

#pragma unroll
  for (int ec = 0; ec < 2; ec++) {
    short8 vf[8];
#pragma unroll
    for (int dk = 0; dk < 8; dk++)
      vf[dk] = *(const short8*)(smem + 32768 +
                ((ew * 64 + ec * 32 + l) * 16 + ((2 * dk + hh) ^ xk)) * 16);
#pragma unroll
    for (int nt = 0; nt < 2; nt++)
#pragma unroll
      for (int dk = 0; dk < 8; dk++) {
        short8 xf = *(const short8*)(smem +
                    ((nw * 64 + nt * 32 + l) * 16 + ((2 * dk + hh) ^ xk)) * 16);
        acc[nt][ec] = MFMA32(xf, vf[dk], acc[nt][ec]);
      }
  }
  __syncthreads();  // X/Vt reads done; region0 becomes output staging [e][n]

  // acc: row=n-local (m = (r&3)+8*(r>>2)+4hh), col=e. Pack 4 consecutive n -> b64.
#pragma unroll
  for (int nt = 0; nt < 2; nt++)
#pragma unroll
    for (int ec = 0; ec < 2; ec++) {
      int e = ew * 64 + ec * 32 + l;
#pragma unroll
      for (int g = 0; g < 4; g++) {
        int u = nw * 8 + nt * 4 + g;
        char* p = smem + (size_t)e * 256 + ((u ^ (e & 7)) * 16) + 8 * hh;
        *(unsigned long long*)p = pack4(acc[nt][ec][4 * g + 0], acc[nt][ec][4 * g + 1],
                                        acc[nt][ec][4 * g + 2], acc[nt][ec][4 * g + 3]);
      }
    }
  __syncthreads();
  char* XVTh = (char*)(XVT + (size_t)h * D * N);
#pragma unroll
  for (int i = 0; i < 8; i++) {
    int s = i * 256 + tid;
    int e = s >> 4, up = s & 15, u = up ^ (e & 7);
    *(uint4*)(XVTh + (size_t)e * 4096 + (size_t)n0 * 2 + u * 16) =
        *(const uint4*)(smem + (size_t)e * 256 + up * 16);
  }
}

// ------------- fused attention: Q-prologue + flash loop, P in registers -------------
__global__ __launch_bounds__(256, 2)
void attn_kernel(const unsigned short* __restrict__ Xb,
                 const unsigned short* __restrict__ Wt,
                 const unsigned short* __restrict__ XVT,
                 float* __restrict__ out) {
  __shared__ __align__(16) char smem[65536];  // region0: X/K/Ls  region1: Wt/V/Ls
  const int bx = blockIdx.x;
  const int h = bx >> 4;
  const int q0 = (bx & 15) << 7;
  const int tid = threadIdx.x;
  const int wave = tid >> 6, lane = tid & 63;
  const int l = lane & 31, hh = lane >> 5, xk = l & 7;
  const int kw = wave & 1, qw = wave >> 1;
  const int lh = lane >> 4, lu = lane & 15;

  const char* XbB = (const char*)Xb;
  const char* WtB = (const char*)(Wt + (size_t)h * D * D);
  const char* XVB = (const char*)(XVT + (size_t)h * D * N);

  // ---- prologue: stage X(q-tile) + Wt[h], compute Q fragments in registers
#pragma unroll
  for (int i = 0; i < 8; i++) {
    int r = wave * 32 + i * 4 + lh;
    int usrc = lu ^ (r & 7);
    load_lds16(XbB + (size_t)(q0 + r) * 256 + usrc * 16, smem + (wave * 8 + i) * 1024);
    load_lds16(WtB + (size_t)r * 256 + usrc * 16, smem + 32768 + (wave * 8 + i) * 1024);
  }
  __syncthreads();

  short8 qf[8][2];  // [dks][qc] : B-frags Q^T[d][q]
  {
    short8 xf[2][8];
#pragma unroll
    for (int qc = 0; qc < 2; qc++)
#pragma unroll
      for (int dk = 0; dk < 8; dk++)
        xf[qc][dk] = *(const short8*)(smem +
                     ((qw * 64 + qc * 32 + l) * 16 + ((2 * dk + hh) ^ xk)) * 16);
#pragma unroll
    for (int et = 0; et < 4; et++) {
      float16v qa0 = (float16v)0.0f, qa1 = (float16v)0.0f;
#pragma unroll
      for (int dk = 0; dk < 8; dk++) {
        short8 wa = *(const short8*)(smem + 32768 +
                     ((et * 32 + l) * 16 + ((2 * dk + hh) ^ xk)) * 16);
        qa0 = MFMA32(wa, xf[0][dk], qa0);
        qa1 = MFMA32(wa, xf[1][dk], qa1);
      }
      regs_to_bfrags(qa0, hh, qf[2 * et][0], qf[2 * et + 1][0]);
      regs_to_bfrags(qa1, hh, qf[2 * et][1], qf[2 * et + 1][1]);
    }
  }

  float16v oacc[4][2];  // [et][qc] : O^T[e][q]
#pragma unroll
  for (int et = 0; et < 4; et++) { oacc[et][0] = (float16v)0.0f; oacc[et][1] = (float16v)0.0f; }
  float lsum[2] = {0.0f, 0.0f};

  for (int kt = 0; kt < N / 128; kt++) {
    const int k0 = kt * 128;
    __syncthreads();  // previous tile (or prologue) readers done
#pragma unroll
    for (int i = 0; i < 8; i++) {
      int r = wave * 32 + i * 4 + lh;
      int usrc = lu ^ (r & 7);
      load_lds16(XbB + (size_t)(k0 + r) * 256 + usrc * 16, smem + (wave * 8 + i) * 1024);
      load_lds16(XVB + (size_t)r * 4096 + (size_t)k0 * 2 + usrc * 16,
                 smem + 32768 + (wave * 8 + i) * 1024);
    }
    __syncthreads();

#pragma unroll
    for (int ksub = 0; ksub < 2; ksub++) {
      short8 pf[2][2];  // [qc][kk]
#pragma unroll
      for (int qc = 0; qc < 2; qc++) {
        float16v s = (float16v)0.0f;
#pragma unroll
        for (int ks = 0; ks < 8; ks++) {
          short8 kf = *(const short8*)(smem +
                      ((kw * 64 + ksub * 32 + l) * 16 + ((2 * ks + hh) ^ xk)) * 16);
          s = MFMA32(kf, qf[ks][qc], s);
        }
        regs_to_pfrags(s, hh, lsum[qc], pf[qc][0], pf[qc][1]);
      }
#pragma unroll
      for (int kk = 0; kk < 2; kk++)
#pragma unroll
        for (int et = 0; et < 4; et++) {
          short8 vf = *(const short8*)(smem + 32768 +
                      ((et * 32 + l) * 16 + ((kw * 8 + ksub * 4 + kk * 2 + hh) ^ xk)) * 16);
          oacc[et][0] = MFMA32(vf, pf[0][kk], oacc[et][0]);
          oacc[et][1] = MFMA32(vf, pf[1][kk], oacc[et][1]);
        }
    }
  }

  // ---- epilogue: combine lsum across kw pair, normalize, coalesced atomics
  __syncthreads();
  float* Lred = (float*)smem;  // [2][128]
#pragma unroll
  for (int qc = 0; qc < 2; qc++) {
    float t = lsum[qc] + __shfl_xor(lsum[qc], 32);
    if (hh == 0) Lred[kw * 128 + qw * 64 + qc * 32 + l] = t;
  }
  __syncthreads();
  float inv[2];
#pragma unroll
  for (int qc = 0; qc < 2; qc++) {
    int q = qw * 64 + qc * 32 + l;
    inv[qc] = 1.0f / (Lred[q] + Lred[128 + q]);
  }
  __syncthreads();  // Lred consumed before Ls overwrite

  // Ls: [128 q][32 units of 16B] fp32, unit-swizzled by (q&7)
#pragma unroll
  for (int pass = 0; pass < 2; pass++) {
    if (kw == pass) {
#pragma unroll
      for (int et = 0; et < 4; et++)
#pragma unroll
        for (int qc = 0; qc < 2; qc++) {
          int q = qw * 64 + qc * 32 + l;
#pragma unroll
          for (int g = 0; g < 4; g++) {
            int u = et * 8 + 2 * g + hh;
            float4v* p = (float4v*)(smem + (size_t)q * 512 + ((u ^ xk) * 16));
            float4v v;
            v.x = oacc[et][qc][4 * g + 0] * inv[qc];
            v.y = oacc[et][qc][4 * g + 1] * inv[qc];
            v.z = oacc[et][qc][4 * g + 2] * inv[qc];
            v.w = oacc[et][qc][4 * g + 3] * inv[qc];
            if (pass == 0) *p = v;
            else { float4v o = *p; o.x += v.x; o.y += v.y; o.z += v.z; o.w += v.w; *p = o; }
          }
        }
    }
    __syncthreads();
  }
#pragma unroll
  for (int i = 0; i < 16; i++) {
    int s = i * 256 + tid;
    int q = s >> 5, up = s & 31, u = up ^ (q & 7);
    float4v v = *(const float4v*)(smem + (size_t)q * 512 + up * 16);
    float* dst = out + (size_t)(q0 + q) * D + u * 4;
    atomicAdd(dst + 0, v.x);
    atomicAdd(dst + 1, v.y);
    atomicAdd(dst + 2, v.z);
    atomicAdd(dst + 3, v.w);
  }
}

extern "C" void kernel_launch(void* const* d_in, const int* in_sizes, int n_in,
                              void* d_out, int out_size, void* d_ws, size_t ws_size,
                              hipStream_t stream) {
  const float* X = (const float*)d_in[0];
  const float* W = (const float*)d_in[1];
  const float* V = (const float*)d_in[2];
  float* out = (float*)d_out;

  unsigned short* Xb = (unsigned short*)d_ws;        // N*D
  unsigned short* Wt = Xb + (size_t)N * D;           // H*D*D (scaled, transposed)
  unsigned short* Vt = Wt + (size_t)H * D * D;       // H*D*D (transposed)
  unsigned short* XVT = Vt + (size_t)H * D * D;      // H*D*N

  hipMemsetAsync(d_out, 0, (size_t)N * D * sizeof(float), stream);

  xconv_kernel<<<dim3(N * D / (256 * 8)), 256, 0, stream>>>(X, Xb);
  wvconv_kernel<<<dim3(2 * H), 256, 0, stream>>>(W, V, Wt, Vt);
  prep_kernel<<<dim3((N / 128) * H), 256, 0, stream>>>(Xb, Vt, XVT);
  attn_kernel<<<dim3((N / 128) * H), 256, 0, stream>>>(Xb, Wt, XVT, out);
}